// Round 3
// baseline (926.177 us; speedup 1.0000x reference)
//
#include <hip/hip_runtime.h>

// -------- graph preprocessing --------

__global__ void k_hist(const int* __restrict__ dst, int E, int* __restrict__ deg) {
    int e = blockIdx.x * blockDim.x + threadIdx.x;
    if (e < E) atomicAdd(&deg[dst[e]], 1);
}

__global__ void k_scan1(const int* __restrict__ deg, int* __restrict__ rowptr,
                        int* __restrict__ bsum, int n) {
    __shared__ int s[256];
    int t = threadIdx.x;
    int base = blockIdx.x * 1024 + t * 4;
    int v0 = (base + 0 < n) ? deg[base + 0] : 0;
    int v1 = (base + 1 < n) ? deg[base + 1] : 0;
    int v2 = (base + 2 < n) ? deg[base + 2] : 0;
    int v3 = (base + 3 < n) ? deg[base + 3] : 0;
    int ts = v0 + v1 + v2 + v3;
    s[t] = ts;
    __syncthreads();
    for (int off = 1; off < 256; off <<= 1) {
        int x = (t >= off) ? s[t - off] : 0;
        __syncthreads();
        s[t] += x;
        __syncthreads();
    }
    int excl = s[t] - ts;
    if (base + 0 < n) rowptr[base + 0] = excl;
    if (base + 1 < n) rowptr[base + 1] = excl + v0;
    if (base + 2 < n) rowptr[base + 2] = excl + v0 + v1;
    if (base + 3 < n) rowptr[base + 3] = excl + v0 + v1 + v2;
    if (t == 255) bsum[blockIdx.x] = s[255];
}

__global__ void k_scan2(int* __restrict__ bsum, int nb) {
    __shared__ int s[256];
    int t = threadIdx.x;
    int v = (t < nb) ? bsum[t] : 0;
    s[t] = v;
    __syncthreads();
    for (int off = 1; off < 256; off <<= 1) {
        int x = (t >= off) ? s[t - off] : 0;
        __syncthreads();
        s[t] += x;
        __syncthreads();
    }
    if (t < nb) bsum[t] = s[t] - v;  // exclusive
}

__global__ void k_scan3(int* __restrict__ rowptr, const int* __restrict__ bsum, int n, int Etot) {
    int i = blockIdx.x * blockDim.x + threadIdx.x;
    if (i < n) rowptr[i] += bsum[i >> 10];
    if (i == 0) rowptr[n] = Etot;
}

__global__ void k_scatter(const int* __restrict__ src, const int* __restrict__ dst, int E,
                          const int* __restrict__ rowptr, int* __restrict__ cursor,
                          int* __restrict__ csr) {
    int e = blockIdx.x * blockDim.x + threadIdx.x;
    if (e < E) {
        int d = dst[e];
        int pos = rowptr[d] + atomicAdd(&cursor[d], 1);
        csr[pos] = src[e];
    }
}

// -------- 4-way fused GEMM: O_i = X @ W_i + b_i, each [n,64] --------

template <int K>
__global__ __launch_bounds__(256) void k_gemm4(
    const float* __restrict__ X, int n,
    const float* __restrict__ W0, const float* __restrict__ b0, float* __restrict__ O0,
    const float* __restrict__ W1, const float* __restrict__ b1, float* __restrict__ O1,
    const float* __restrict__ W2, const float* __restrict__ b2, float* __restrict__ O2,
    const float* __restrict__ W3, const float* __restrict__ b3, float* __restrict__ O3) {
    const float* W;
    const float* B;
    float* O;
    switch (blockIdx.y) {
        case 0: W = W0; B = b0; O = O0; break;
        case 1: W = W1; B = b1; O = O1; break;
        case 2: W = W2; B = b2; O = O2; break;
        default: W = W3; B = b3; O = O3; break;
    }
    __shared__ float xs[64][K + 4];   // +4 pad: keeps 16B alignment, kills bank conflicts
    __shared__ float wsh[K][64];
    int t = threadIdx.x;
    int row0 = blockIdx.x * 64;

    // stage W [K][64]
    for (int idx = t * 4; idx < K * 64; idx += 1024) {
        *(float4*)(&wsh[0][0] + idx) = *(const float4*)(W + idx);
    }
    // stage X tile [64][K]
    for (int idx = t * 4; idx < 64 * K; idx += 1024) {
        int r = idx / K, c = idx % K;
        int grow = row0 + r;
        float4 xv = make_float4(0.f, 0.f, 0.f, 0.f);
        if (grow < n) xv = *(const float4*)(X + (size_t)grow * K + c);
        *(float4*)(&xs[r][c]) = xv;
    }
    __syncthreads();

    int tx = t & 15, ty = t >> 4;
    int c0 = tx * 4, r0 = ty * 4;
    float acc[4][4] = {};
    for (int k2 = 0; k2 < K; ++k2) {
        float a0 = xs[r0 + 0][k2];
        float a1 = xs[r0 + 1][k2];
        float a2 = xs[r0 + 2][k2];
        float a3 = xs[r0 + 3][k2];
        float4 b4 = *(const float4*)(&wsh[k2][c0]);
        acc[0][0] += a0 * b4.x; acc[0][1] += a0 * b4.y; acc[0][2] += a0 * b4.z; acc[0][3] += a0 * b4.w;
        acc[1][0] += a1 * b4.x; acc[1][1] += a1 * b4.y; acc[1][2] += a1 * b4.z; acc[1][3] += a1 * b4.w;
        acc[2][0] += a2 * b4.x; acc[2][1] += a2 * b4.y; acc[2][2] += a2 * b4.z; acc[2][3] += a2 * b4.w;
        acc[3][0] += a3 * b4.x; acc[3][1] += a3 * b4.y; acc[3][2] += a3 * b4.z; acc[3][3] += a3 * b4.w;
    }
    float4 bias4 = *(const float4*)(B + c0);
    for (int i = 0; i < 4; ++i) {
        int grow = row0 + r0 + i;
        if (grow < n) {
            float4 o;
            o.x = acc[i][0] + bias4.x;
            o.y = acc[i][1] + bias4.y;
            o.z = acc[i][2] + bias4.z;
            o.w = acc[i][3] + bias4.w;
            *(float4*)(O + (size_t)grow * 64 + c0) = o;
        }
    }
}

// -------- fused attention: one wave per destination node --------
// out[i] = (sum_j exp(q_i.k_j/8) v_j) / max(sum_j exp(q_i.k_j/8), 1e-16) + skip[i]

__global__ __launch_bounds__(256) void k_attn(
    const float* __restrict__ q, const float* __restrict__ kk, const float* __restrict__ vv,
    const float* __restrict__ skip, const int* __restrict__ rowptr, const int* __restrict__ csr,
    float* __restrict__ out, int n, int dorelu) {
    int wid = threadIdx.x >> 6, lane = threadIdx.x & 63;
    int node = blockIdx.x * 4 + wid;
    if (node >= n) return;
    int start = rowptr[node];
    int deg = rowptr[node + 1] - start;
    float qc = q[(size_t)node * 64 + lane];
    float sumex = 0.f, acc = 0.f;
    for (int j = 0; j < deg; ++j) {
        int s_ = csr[start + j];
        float p = qc * kk[(size_t)s_ * 64 + lane];
        p += __shfl_xor(p, 32);
        p += __shfl_xor(p, 16);
        p += __shfl_xor(p, 8);
        p += __shfl_xor(p, 4);
        p += __shfl_xor(p, 2);
        p += __shfl_xor(p, 1);
        float ex = expf(p * 0.125f);  // 1/sqrt(64)
        sumex += ex;
        acc += ex * vv[(size_t)s_ * 64 + lane];
    }
    float rtot = 1.0f / fmaxf(sumex, 1e-16f);
    float val = acc * rtot + skip[(size_t)node * 64 + lane];
    if (dorelu) val = fmaxf(val, 0.f);
    out[(size_t)node * 64 + lane] = val;
}

// -------- launch --------

extern "C" void kernel_launch(void* const* d_in, const int* in_sizes, int n_in,
                              void* d_out, int out_size, void* d_ws, size_t ws_size,
                              hipStream_t stream) {
    const float* x = (const float*)d_in[0];
    const int* ei = (const int*)d_in[1];
    // d_in[2] = edge_attr (ignored, edge_dim=None)
    const float* Wq1 = (const float*)d_in[3];  const float* bq1 = (const float*)d_in[4];
    const float* Wk1 = (const float*)d_in[5];  const float* bk1 = (const float*)d_in[6];
    const float* Wv1 = (const float*)d_in[7];  const float* bv1 = (const float*)d_in[8];
    const float* Ws1 = (const float*)d_in[9];  const float* bs1 = (const float*)d_in[10];
    const float* Wq2 = (const float*)d_in[11]; const float* bq2 = (const float*)d_in[12];
    const float* Wk2 = (const float*)d_in[13]; const float* bk2 = (const float*)d_in[14];
    const float* Wv2 = (const float*)d_in[15]; const float* bv2 = (const float*)d_in[16];
    const float* Ws2 = (const float*)d_in[17]; const float* bs2 = (const float*)d_in[18];

    const int N = in_sizes[0] / 128;
    const int E = in_sizes[1] / 2;
    const int* srcI = ei;
    const int* dstI = ei + E;

    char* w = (char*)d_ws;
    auto alloc = [&](size_t bytes) {
        void* p = (void*)w;
        w += (bytes + 255) & ~(size_t)255;
        return p;
    };
    int* deg    = (int*)alloc((size_t)N * 4);
    int* cursor = (int*)alloc((size_t)N * 4);
    int* rowptr = (int*)alloc((size_t)(N + 1) * 4);
    int* bsum   = (int*)alloc(256 * 4);
    int* csr    = (int*)alloc((size_t)E * 4);
    float* qb   = (float*)alloc((size_t)N * 64 * 4);
    float* kb   = (float*)alloc((size_t)N * 64 * 4);
    float* vb   = (float*)alloc((size_t)N * 64 * 4);
    float* sb   = (float*)alloc((size_t)N * 64 * 4);
    float* hb   = (float*)alloc((size_t)N * 64 * 4);

    hipMemsetAsync(deg, 0, (size_t)N * 4, stream);
    hipMemsetAsync(cursor, 0, (size_t)N * 4, stream);

    k_hist<<<(E + 255) / 256, 256, 0, stream>>>(dstI, E, deg);
    int nb = (N + 1023) / 1024;
    k_scan1<<<nb, 256, 0, stream>>>(deg, rowptr, bsum, N);
    k_scan2<<<1, 256, 0, stream>>>(bsum, nb);
    k_scan3<<<(N + 255) / 256, 256, 0, stream>>>(rowptr, bsum, N, E);
    k_scatter<<<(E + 255) / 256, 256, 0, stream>>>(srcI, dstI, E, rowptr, cursor, csr);

    dim3 gg((N + 63) / 64, 4);
    // layer 1
    k_gemm4<128><<<gg, 256, 0, stream>>>(x, N, Wq1, bq1, qb, Wk1, bk1, kb,
                                         Wv1, bv1, vb, Ws1, bs1, sb);
    k_attn<<<(N + 3) / 4, 256, 0, stream>>>(qb, kb, vb, sb, rowptr, csr, hb, N, 1);
    // layer 2
    k_gemm4<64><<<gg, 256, 0, stream>>>(hb, N, Wq2, bq2, qb, Wk2, bk2, kb,
                                        Wv2, bv2, vb, Ws2, bs2, sb);
    k_attn<<<(N + 3) / 4, 256, 0, stream>>>(qb, kb, vb, sb, rowptr, csr, (float*)d_out, N, 0);
}

// Round 6
// 697.532 us; speedup vs baseline: 1.3278x; 1.3278x over previous
//
#include <hip/hip_runtime.h>

__device__ __forceinline__ unsigned short f2bf(float f) {
    unsigned u = __float_as_uint(f);
    unsigned r = (u + 0x7fff + ((u >> 16) & 1)) >> 16;  // RNE
    return (unsigned short)r;
}
__device__ __forceinline__ float bf2f(unsigned short h) {
    return __uint_as_float(((unsigned)h) << 16);
}

// -------- graph preprocessing --------

__global__ void k_hist(const int* __restrict__ dst, int E, int* __restrict__ deg) {
    int e = blockIdx.x * blockDim.x + threadIdx.x;
    if (e < E) atomicAdd(&deg[dst[e]], 1);
}

__global__ void k_scan1(const int* __restrict__ deg, int* __restrict__ rowptr,
                        int* __restrict__ bsum, int n) {
    __shared__ int s[256];
    int t = threadIdx.x;
    int base = blockIdx.x * 1024 + t * 4;
    int v0 = (base + 0 < n) ? deg[base + 0] : 0;
    int v1 = (base + 1 < n) ? deg[base + 1] : 0;
    int v2 = (base + 2 < n) ? deg[base + 2] : 0;
    int v3 = (base + 3 < n) ? deg[base + 3] : 0;
    int ts = v0 + v1 + v2 + v3;
    s[t] = ts;
    __syncthreads();
    for (int off = 1; off < 256; off <<= 1) {
        int x = (t >= off) ? s[t - off] : 0;
        __syncthreads();
        s[t] += x;
        __syncthreads();
    }
    int excl = s[t] - ts;
    if (base + 0 < n) rowptr[base + 0] = excl;
    if (base + 1 < n) rowptr[base + 1] = excl + v0;
    if (base + 2 < n) rowptr[base + 2] = excl + v0 + v1;
    if (base + 3 < n) rowptr[base + 3] = excl + v0 + v1 + v2;
    if (t == 255) bsum[blockIdx.x] = s[255];
}

__global__ void k_scan2(int* __restrict__ bsum, int nb) {
    __shared__ int s[256];
    int t = threadIdx.x;
    int v = (t < nb) ? bsum[t] : 0;
    s[t] = v;
    __syncthreads();
    for (int off = 1; off < 256; off <<= 1) {
        int x = (t >= off) ? s[t - off] : 0;
        __syncthreads();
        s[t] += x;
        __syncthreads();
    }
    if (t < nb) bsum[t] = s[t] - v;  // exclusive
}

__global__ void k_scan3(int* __restrict__ rowptr, const int* __restrict__ bsum, int n, int Etot) {
    int i = blockIdx.x * blockDim.x + threadIdx.x;
    if (i < n) rowptr[i] += bsum[i >> 10];
    if (i == 0) rowptr[n] = Etot;
}

__global__ void k_scatter(const int* __restrict__ src, const int* __restrict__ dst, int E,
                          const int* __restrict__ rowptr, int* __restrict__ cursor,
                          int* __restrict__ csr) {
    int e = blockIdx.x * blockDim.x + threadIdx.x;
    if (e < E) {
        int d = dst[e];
        int pos = rowptr[d] + atomicAdd(&cursor[d], 1);
        csr[pos] = src[e];
    }
}

// -------- 4-way fused GEMM: O_i = X @ W_i + b_i, each [n,64] --------
// slots 1,2 (k,v) are written as bf16 for the attention gather phase.

template <int K>
__global__ __launch_bounds__(256) void k_gemm4(
    const float* __restrict__ X, int n,
    const float* __restrict__ W0, const float* __restrict__ b0, void* __restrict__ O0,
    const float* __restrict__ W1, const float* __restrict__ b1, void* __restrict__ O1,
    const float* __restrict__ W2, const float* __restrict__ b2, void* __restrict__ O2,
    const float* __restrict__ W3, const float* __restrict__ b3, void* __restrict__ O3) {
    const float* W;
    const float* B;
    void* O;
    switch (blockIdx.y) {
        case 0: W = W0; B = b0; O = O0; break;
        case 1: W = W1; B = b1; O = O1; break;
        case 2: W = W2; B = b2; O = O2; break;
        default: W = W3; B = b3; O = O3; break;
    }
    const bool isbf = (blockIdx.y == 1 || blockIdx.y == 2);
    __shared__ float xs[64][K + 4];   // +4 pad keeps 16B alignment, kills bank conflicts
    __shared__ float wsh[K][64];
    int t = threadIdx.x;
    int row0 = blockIdx.x * 64;

    // stage W [K][64]
    for (int idx = t * 4; idx < K * 64; idx += 1024) {
        *(float4*)(&wsh[0][0] + idx) = *(const float4*)(W + idx);
    }
    // stage X tile [64][K]
    for (int idx = t * 4; idx < 64 * K; idx += 1024) {
        int r = idx / K, c = idx % K;
        int grow = row0 + r;
        float4 xv = make_float4(0.f, 0.f, 0.f, 0.f);
        if (grow < n) xv = *(const float4*)(X + (size_t)grow * K + c);
        *(float4*)(&xs[r][c]) = xv;
    }
    __syncthreads();

    int tx = t & 15, ty = t >> 4;
    int c0 = tx * 4, r0 = ty * 4;
    float acc[4][4] = {};
    for (int k2 = 0; k2 < K; ++k2) {
        float a0 = xs[r0 + 0][k2];
        float a1 = xs[r0 + 1][k2];
        float a2 = xs[r0 + 2][k2];
        float a3 = xs[r0 + 3][k2];
        float4 b4 = *(const float4*)(&wsh[k2][c0]);
        acc[0][0] += a0 * b4.x; acc[0][1] += a0 * b4.y; acc[0][2] += a0 * b4.z; acc[0][3] += a0 * b4.w;
        acc[1][0] += a1 * b4.x; acc[1][1] += a1 * b4.y; acc[1][2] += a1 * b4.z; acc[1][3] += a1 * b4.w;
        acc[2][0] += a2 * b4.x; acc[2][1] += a2 * b4.y; acc[2][2] += a2 * b4.z; acc[2][3] += a2 * b4.w;
        acc[3][0] += a3 * b4.x; acc[3][1] += a3 * b4.y; acc[3][2] += a3 * b4.z; acc[3][3] += a3 * b4.w;
    }
    float4 bias4 = *(const float4*)(B + c0);
    for (int i = 0; i < 4; ++i) {
        int grow = row0 + r0 + i;
        if (grow < n) {
            float4 o;
            o.x = acc[i][0] + bias4.x;
            o.y = acc[i][1] + bias4.y;
            o.z = acc[i][2] + bias4.z;
            o.w = acc[i][3] + bias4.w;
            if (isbf) {
                ushort4 st;
                st.x = f2bf(o.x); st.y = f2bf(o.y); st.z = f2bf(o.z); st.w = f2bf(o.w);
                *(ushort4*)((unsigned short*)O + (size_t)grow * 64 + c0) = st;
            } else {
                *(float4*)((float*)O + (size_t)grow * 64 + c0) = o;
            }
        }
    }
}

// -------- fused attention: one wave per destination node --------
// 16 lanes per edge (float4 channels), 4 edges in flight per wave iteration.
// out[i] = (sum_j exp(q_i.k_j/8) v_j) / max(sum_j exp(q_i.k_j/8), 1e-16) + skip[i]

__global__ __launch_bounds__(256) void k_attn(
    const float* __restrict__ q, const unsigned short* __restrict__ kk,
    const unsigned short* __restrict__ vv,
    const float* __restrict__ skip, const int* __restrict__ rowptr, const int* __restrict__ csr,
    float* __restrict__ out, int n, int dorelu) {
    int wid = threadIdx.x >> 6, lane = threadIdx.x & 63;
    int node = blockIdx.x * 4 + wid;
    if (node >= n) return;
    int start = rowptr[node];
    int deg = rowptr[node + 1] - start;
    int g = lane >> 4;    // edge slot within wave
    int cl = lane & 15;   // channel quad
    float4 q4 = *(const float4*)(q + (size_t)node * 64 + cl * 4);
    float4 acc = make_float4(0.f, 0.f, 0.f, 0.f);
    float sumex = 0.f;
#pragma unroll 2
    for (int j0 = 0; j0 < deg; j0 += 4) {
        int jj = j0 + g;
        bool act = jj < deg;
        int s_ = act ? csr[start + jj] : 0;
        ushort4 kraw = make_ushort4(0, 0, 0, 0);
        if (act) kraw = *(const ushort4*)(kk + (size_t)s_ * 64 + cl * 4);
        float d = q4.x * bf2f(kraw.x) + q4.y * bf2f(kraw.y) +
                  q4.z * bf2f(kraw.z) + q4.w * bf2f(kraw.w);
        d += __shfl_xor(d, 1);
        d += __shfl_xor(d, 2);
        d += __shfl_xor(d, 4);
        d += __shfl_xor(d, 8);
        float ex = act ? __expf(d * 0.125f) : 0.f;  // 1/sqrt(64)
        sumex += ex;
        ushort4 vraw = make_ushort4(0, 0, 0, 0);
        if (act) vraw = *(const ushort4*)(vv + (size_t)s_ * 64 + cl * 4);
        acc.x += ex * bf2f(vraw.x);
        acc.y += ex * bf2f(vraw.y);
        acc.z += ex * bf2f(vraw.z);
        acc.w += ex * bf2f(vraw.w);
    }
    // reduce the 4 edge-groups
    acc.x += __shfl_xor(acc.x, 16); acc.x += __shfl_xor(acc.x, 32);
    acc.y += __shfl_xor(acc.y, 16); acc.y += __shfl_xor(acc.y, 32);
    acc.z += __shfl_xor(acc.z, 16); acc.z += __shfl_xor(acc.z, 32);
    acc.w += __shfl_xor(acc.w, 16); acc.w += __shfl_xor(acc.w, 32);
    sumex += __shfl_xor(sumex, 16); sumex += __shfl_xor(sumex, 32);
    if (g == 0) {
        float r = 1.0f / fmaxf(sumex, 1e-16f);
        float4 sk = *(const float4*)(skip + (size_t)node * 64 + cl * 4);
        float4 o;
        o.x = acc.x * r + sk.x;
        o.y = acc.y * r + sk.y;
        o.z = acc.z * r + sk.z;
        o.w = acc.w * r + sk.w;
        if (dorelu) {
            o.x = fmaxf(o.x, 0.f); o.y = fmaxf(o.y, 0.f);
            o.z = fmaxf(o.z, 0.f); o.w = fmaxf(o.w, 0.f);
        }
        *(float4*)(out + (size_t)node * 64 + cl * 4) = o;
    }
}

// -------- launch --------

extern "C" void kernel_launch(void* const* d_in, const int* in_sizes, int n_in,
                              void* d_out, int out_size, void* d_ws, size_t ws_size,
                              hipStream_t stream) {
    const float* x = (const float*)d_in[0];
    const int* ei = (const int*)d_in[1];
    // d_in[2] = edge_attr (ignored, edge_dim=None)
    const float* Wq1 = (const float*)d_in[3];  const float* bq1 = (const float*)d_in[4];
    const float* Wk1 = (const float*)d_in[5];  const float* bk1 = (const float*)d_in[6];
    const float* Wv1 = (const float*)d_in[7];  const float* bv1 = (const float*)d_in[8];
    const float* Ws1 = (const float*)d_in[9];  const float* bs1 = (const float*)d_in[10];
    const float* Wq2 = (const float*)d_in[11]; const float* bq2 = (const float*)d_in[12];
    const float* Wk2 = (const float*)d_in[13]; const float* bk2 = (const float*)d_in[14];
    const float* Wv2 = (const float*)d_in[15]; const float* bv2 = (const float*)d_in[16];
    const float* Ws2 = (const float*)d_in[17]; const float* bs2 = (const float*)d_in[18];

    const int N = in_sizes[0] / 128;
    const int E = in_sizes[1] / 2;
    const int* srcI = ei;
    const int* dstI = ei + E;

    char* w = (char*)d_ws;
    auto alloc = [&](size_t bytes) {
        void* p = (void*)w;
        w += (bytes + 255) & ~(size_t)255;
        return p;
    };
    int* deg    = (int*)alloc((size_t)N * 4);
    int* cursor = (int*)alloc((size_t)N * 4);
    int* rowptr = (int*)alloc((size_t)(N + 1) * 4);
    int* bsum   = (int*)alloc(256 * 4);
    int* csr    = (int*)alloc((size_t)E * 4);
    float* qb            = (float*)alloc((size_t)N * 64 * 4);
    unsigned short* kb   = (unsigned short*)alloc((size_t)N * 64 * 2);
    unsigned short* vb   = (unsigned short*)alloc((size_t)N * 64 * 2);
    float* sb            = (float*)alloc((size_t)N * 64 * 4);
    float* hb            = (float*)alloc((size_t)N * 64 * 4);

    hipMemsetAsync(deg, 0, (size_t)N * 4, stream);
    hipMemsetAsync(cursor, 0, (size_t)N * 4, stream);

    k_hist<<<(E + 255) / 256, 256, 0, stream>>>(dstI, E, deg);
    int nb = (N + 1023) / 1024;
    k_scan1<<<nb, 256, 0, stream>>>(deg, rowptr, bsum, N);
    k_scan2<<<1, 256, 0, stream>>>(bsum, nb);
    k_scan3<<<(N + 255) / 256, 256, 0, stream>>>(rowptr, bsum, N, E);
    k_scatter<<<(E + 255) / 256, 256, 0, stream>>>(srcI, dstI, E, rowptr, cursor, csr);

    dim3 gg((N + 63) / 64, 4);
    // layer 1
    k_gemm4<128><<<gg, 256, 0, stream>>>(x, N, Wq1, bq1, qb, Wk1, bk1, kb,
                                         Wv1, bv1, vb, Ws1, bs1, sb);
    k_attn<<<(N + 3) / 4, 256, 0, stream>>>(qb, kb, vb, sb, rowptr, csr, hb, N, 1);
    // layer 2
    k_gemm4<64><<<gg, 256, 0, stream>>>(hb, N, Wq2, bq2, qb, Wk2, bk2, kb,
                                        Wv2, bv2, vb, Ws2, bs2, sb);
    k_attn<<<(N + 3) / 4, 256, 0, stream>>>(qb, kb, vb, sb, rowptr, csr, (float*)d_out, N, 0);
}

// Round 7
// 625.595 us; speedup vs baseline: 1.4805x; 1.1150x over previous
//
#include <hip/hip_runtime.h>

typedef __attribute__((ext_vector_type(8))) short short8;
typedef __attribute__((ext_vector_type(4))) float f32x4;

__device__ __forceinline__ unsigned short f2bf(float f) {
    unsigned u = __float_as_uint(f);
    unsigned r = (u + 0x7fff + ((u >> 16) & 1)) >> 16;  // RNE
    return (unsigned short)r;
}
__device__ __forceinline__ float bf2f(unsigned short h) {
    return __uint_as_float(((unsigned)h) << 16);
}

// -------- graph preprocessing --------

__global__ void k_hist(const int* __restrict__ dst, int E, int* __restrict__ deg) {
    int e = blockIdx.x * blockDim.x + threadIdx.x;
    if (e < E) atomicAdd(&deg[dst[e]], 1);
}

__global__ void k_scan1(const int* __restrict__ deg, int* __restrict__ rowptr,
                        int* __restrict__ bsum, int n) {
    __shared__ int s[256];
    int t = threadIdx.x;
    int base = blockIdx.x * 1024 + t * 4;
    int v0 = (base + 0 < n) ? deg[base + 0] : 0;
    int v1 = (base + 1 < n) ? deg[base + 1] : 0;
    int v2 = (base + 2 < n) ? deg[base + 2] : 0;
    int v3 = (base + 3 < n) ? deg[base + 3] : 0;
    int ts = v0 + v1 + v2 + v3;
    s[t] = ts;
    __syncthreads();
    for (int off = 1; off < 256; off <<= 1) {
        int x = (t >= off) ? s[t - off] : 0;
        __syncthreads();
        s[t] += x;
        __syncthreads();
    }
    int excl = s[t] - ts;
    if (base + 0 < n) rowptr[base + 0] = excl;
    if (base + 1 < n) rowptr[base + 1] = excl + v0;
    if (base + 2 < n) rowptr[base + 2] = excl + v0 + v1;
    if (base + 3 < n) rowptr[base + 3] = excl + v0 + v1 + v2;
    if (t == 255) bsum[blockIdx.x] = s[255];
}

__global__ void k_scan2(int* __restrict__ bsum, int nb) {
    __shared__ int s[256];
    int t = threadIdx.x;
    int v = (t < nb) ? bsum[t] : 0;
    s[t] = v;
    __syncthreads();
    for (int off = 1; off < 256; off <<= 1) {
        int x = (t >= off) ? s[t - off] : 0;
        __syncthreads();
        s[t] += x;
        __syncthreads();
    }
    if (t < nb) bsum[t] = s[t] - v;  // exclusive
}

__global__ void k_scan3(int* __restrict__ rowptr, const int* __restrict__ bsum, int n, int Etot) {
    int i = blockIdx.x * blockDim.x + threadIdx.x;
    if (i < n) rowptr[i] += bsum[i >> 10];
    if (i == 0) rowptr[n] = Etot;
}

__global__ void k_scatter(const int* __restrict__ src, const int* __restrict__ dst, int E,
                          const int* __restrict__ rowptr, int* __restrict__ cursor,
                          int* __restrict__ csr) {
    int e = blockIdx.x * blockDim.x + threadIdx.x;
    if (e < E) {
        int d = dst[e];
        int pos = rowptr[d] + atomicAdd(&cursor[d], 1);
        csr[pos] = src[e];
    }
}

// -------- dtype conversion --------

__global__ void k_cvtX(const float* __restrict__ X, unsigned short* __restrict__ Xbf, int total4) {
    int i = blockIdx.x * blockDim.x + threadIdx.x;
    if (i < total4) {
        float4 v = *(const float4*)(X + (size_t)i * 4);
        ushort4 o;
        o.x = f2bf(v.x); o.y = f2bf(v.y); o.z = f2bf(v.z); o.w = f2bf(v.w);
        *(ushort4*)(Xbf + (size_t)i * 4) = o;
    }
}

// WT[slot][64][K] = bf16( W_slot[k][j] )  (transposed so B-fragment k-runs are contiguous)
__global__ void k_cvtW(const float* __restrict__ W0, const float* __restrict__ W1,
                       const float* __restrict__ W2, const float* __restrict__ W3,
                       unsigned short* __restrict__ WT, int K) {
    int idx = blockIdx.x * blockDim.x + threadIdx.x;
    int tot = 4 * 64 * K;
    if (idx >= tot) return;
    int slot = idx / (64 * K);
    int rem = idx % (64 * K);
    int j = rem / K, k = rem % K;
    const float* W = (slot == 0) ? W0 : (slot == 1) ? W1 : (slot == 2) ? W2 : W3;
    WT[idx] = f2bf(W[k * 64 + j]);
}

// -------- MFMA GEMM: O_slot = Xbf @ W_slot + b_slot,  [n,64] per slot --------
// 64-row tile per block, 4 waves: wave w = rows w*16..w*16+15, all 64 cols.
// LDS tiles [64][K] bf16, XOR-swizzled (byte ^= (row&7)<<4) for conflict-free ds_read_b128.

template <int K>
__global__ __launch_bounds__(256) void k_gemm_mfma(
    const unsigned short* __restrict__ Xbf, int n,
    const unsigned short* __restrict__ WT,
    const float* __restrict__ b0, const float* __restrict__ b1,
    const float* __restrict__ b2, const float* __restrict__ b3,
    void* __restrict__ O0, void* __restrict__ O1,
    void* __restrict__ O2, void* __restrict__ O3) {
    const int slot = blockIdx.y;
    const float* B = (slot == 0) ? b0 : (slot == 1) ? b1 : (slot == 2) ? b2 : b3;
    void* O = (slot == 0) ? O0 : (slot == 1) ? O1 : (slot == 2) ? O2 : O3;
    const bool isbf = (slot == 1 || slot == 2);

    __shared__ unsigned short xs[64 * K];
    __shared__ unsigned short ws[64 * K];
    const int t = threadIdx.x;
    const int row0 = blockIdx.x * 64;
    const int K2 = K * 2;              // bytes per row
    const int CPR = K / 8;             // 16B chunks per row

    // stage X tile (row-guarded) and W^T slot, both swizzled
    const unsigned short* wslot = WT + (size_t)slot * 64 * K;
    for (int c = t; c < 64 * CPR; c += 256) {
        int row = c / CPR, chunk = c % CPR;
        int grow = row0 + row;
        uint4 v = make_uint4(0, 0, 0, 0);
        if (grow < n) v = *(const uint4*)(Xbf + (size_t)grow * K + chunk * 8);
        int byte = (row * K2 + chunk * 16) ^ ((row & 7) << 4);
        *(uint4*)((char*)xs + byte) = v;
        uint4 wv = *(const uint4*)(wslot + (size_t)row * K + chunk * 8);
        *(uint4*)((char*)ws + byte) = wv;
    }
    __syncthreads();

    const int w = t >> 6, l = t & 63;
    const int lr = l & 15, lg = l >> 4;
    f32x4 acc[4];
#pragma unroll
    for (int j = 0; j < 4; ++j) acc[j] = (f32x4){0.f, 0.f, 0.f, 0.f};

#pragma unroll
    for (int ks = 0; ks < K / 32; ++ks) {
        int kb_ = (ks * 32 + lg * 8) * 2;                    // byte offset of k-run
        int arow = w * 16 + lr;
        short8 a = *(const short8*)((char*)xs + ((arow * K2 + kb_) ^ ((arow & 7) << 4)));
#pragma unroll
        for (int j = 0; j < 4; ++j) {
            int brow = j * 16 + lr;
            short8 b = *(const short8*)((char*)ws + ((brow * K2 + kb_) ^ ((brow & 7) << 4)));
            acc[j] = __builtin_amdgcn_mfma_f32_16x16x32_bf16(a, b, acc[j], 0, 0, 0);
        }
    }

    // C/D: col = lane&15, row(within 16) = (lane>>4)*4 + reg
#pragma unroll
    for (int j = 0; j < 4; ++j) {
        int col = j * 16 + lr;
        float bv = B[col];
#pragma unroll
        for (int r = 0; r < 4; ++r) {
            int grow = row0 + w * 16 + lg * 4 + r;
            if (grow < n) {
                float val = acc[j][r] + bv;
                if (isbf) ((unsigned short*)O)[(size_t)grow * 64 + col] = f2bf(val);
                else      ((float*)O)[(size_t)grow * 64 + col] = val;
            }
        }
    }
}

// -------- fused attention: one wave per destination node --------
// 16 lanes per edge (float4 channels), 4 edges in flight per wave iteration.
// obf: write output as bf16 (layer-1 h, feeds next MFMA GEMM) vs f32 (final out).

__global__ __launch_bounds__(256) void k_attn(
    const float* __restrict__ q, const unsigned short* __restrict__ kk,
    const unsigned short* __restrict__ vv,
    const float* __restrict__ skip, const int* __restrict__ rowptr, const int* __restrict__ csr,
    void* __restrict__ out, int n, int dorelu, int obf) {
    int wid = threadIdx.x >> 6, lane = threadIdx.x & 63;
    int node = blockIdx.x * 4 + wid;
    if (node >= n) return;
    int start = rowptr[node];
    int deg = rowptr[node + 1] - start;
    int g = lane >> 4;    // edge slot within wave
    int cl = lane & 15;   // channel quad
    float4 q4 = *(const float4*)(q + (size_t)node * 64 + cl * 4);
    float4 acc = make_float4(0.f, 0.f, 0.f, 0.f);
    float sumex = 0.f;
#pragma unroll 2
    for (int j0 = 0; j0 < deg; j0 += 4) {
        int jj = j0 + g;
        bool act = jj < deg;
        int s_ = act ? csr[start + jj] : 0;
        ushort4 kraw = make_ushort4(0, 0, 0, 0);
        if (act) kraw = *(const ushort4*)(kk + (size_t)s_ * 64 + cl * 4);
        float d = q4.x * bf2f(kraw.x) + q4.y * bf2f(kraw.y) +
                  q4.z * bf2f(kraw.z) + q4.w * bf2f(kraw.w);
        d += __shfl_xor(d, 1);
        d += __shfl_xor(d, 2);
        d += __shfl_xor(d, 4);
        d += __shfl_xor(d, 8);
        float ex = act ? __expf(d * 0.125f) : 0.f;  // 1/sqrt(64)
        sumex += ex;
        ushort4 vraw = make_ushort4(0, 0, 0, 0);
        if (act) vraw = *(const ushort4*)(vv + (size_t)s_ * 64 + cl * 4);
        acc.x += ex * bf2f(vraw.x);
        acc.y += ex * bf2f(vraw.y);
        acc.z += ex * bf2f(vraw.z);
        acc.w += ex * bf2f(vraw.w);
    }
    acc.x += __shfl_xor(acc.x, 16); acc.x += __shfl_xor(acc.x, 32);
    acc.y += __shfl_xor(acc.y, 16); acc.y += __shfl_xor(acc.y, 32);
    acc.z += __shfl_xor(acc.z, 16); acc.z += __shfl_xor(acc.z, 32);
    acc.w += __shfl_xor(acc.w, 16); acc.w += __shfl_xor(acc.w, 32);
    sumex += __shfl_xor(sumex, 16); sumex += __shfl_xor(sumex, 32);
    if (g == 0) {
        float r = 1.0f / fmaxf(sumex, 1e-16f);
        float4 sk = *(const float4*)(skip + (size_t)node * 64 + cl * 4);
        float4 o;
        o.x = acc.x * r + sk.x;
        o.y = acc.y * r + sk.y;
        o.z = acc.z * r + sk.z;
        o.w = acc.w * r + sk.w;
        if (dorelu) {
            o.x = fmaxf(o.x, 0.f); o.y = fmaxf(o.y, 0.f);
            o.z = fmaxf(o.z, 0.f); o.w = fmaxf(o.w, 0.f);
        }
        if (obf) {
            ushort4 st;
            st.x = f2bf(o.x); st.y = f2bf(o.y); st.z = f2bf(o.z); st.w = f2bf(o.w);
            *(ushort4*)((unsigned short*)out + (size_t)node * 64 + cl * 4) = st;
        } else {
            *(float4*)((float*)out + (size_t)node * 64 + cl * 4) = o;
        }
    }
}

// -------- launch --------

extern "C" void kernel_launch(void* const* d_in, const int* in_sizes, int n_in,
                              void* d_out, int out_size, void* d_ws, size_t ws_size,
                              hipStream_t stream) {
    const float* x = (const float*)d_in[0];
    const int* ei = (const int*)d_in[1];
    // d_in[2] = edge_attr (ignored, edge_dim=None)
    const float* Wq1 = (const float*)d_in[3];  const float* bq1 = (const float*)d_in[4];
    const float* Wk1 = (const float*)d_in[5];  const float* bk1 = (const float*)d_in[6];
    const float* Wv1 = (const float*)d_in[7];  const float* bv1 = (const float*)d_in[8];
    const float* Ws1 = (const float*)d_in[9];  const float* bs1 = (const float*)d_in[10];
    const float* Wq2 = (const float*)d_in[11]; const float* bq2 = (const float*)d_in[12];
    const float* Wk2 = (const float*)d_in[13]; const float* bk2 = (const float*)d_in[14];
    const float* Wv2 = (const float*)d_in[15]; const float* bv2 = (const float*)d_in[16];
    const float* Ws2 = (const float*)d_in[17]; const float* bs2 = (const float*)d_in[18];

    const int N = in_sizes[0] / 128;
    const int E = in_sizes[1] / 2;
    const int* srcI = ei;
    const int* dstI = ei + E;

    char* w = (char*)d_ws;
    auto alloc = [&](size_t bytes) {
        void* p = (void*)w;
        w += (bytes + 255) & ~(size_t)255;
        return p;
    };
    int* deg    = (int*)alloc((size_t)N * 4);
    int* cursor = (int*)alloc((size_t)N * 4);
    int* rowptr = (int*)alloc((size_t)(N + 1) * 4);
    int* bsum   = (int*)alloc(256 * 4);
    int* csr    = (int*)alloc((size_t)E * 4);
    float* qb          = (float*)alloc((size_t)N * 64 * 4);
    unsigned short* kb = (unsigned short*)alloc((size_t)N * 64 * 2);
    unsigned short* vb = (unsigned short*)alloc((size_t)N * 64 * 2);
    float* sb          = (float*)alloc((size_t)N * 64 * 4);
    unsigned short* xbf = (unsigned short*)alloc((size_t)N * 128 * 2);  // layer-1 bf16 input
    unsigned short* hbf = xbf;  // alias: xbf dead after gemm1; hbf written by attn1 (N*64 <= N*128)
    unsigned short* WT1 = (unsigned short*)alloc((size_t)4 * 64 * 128 * 2);
    unsigned short* WT2 = (unsigned short*)alloc((size_t)4 * 64 * 64 * 2);

    hipMemsetAsync(deg, 0, (size_t)N * 4, stream);
    hipMemsetAsync(cursor, 0, (size_t)N * 4, stream);

    k_hist<<<(E + 255) / 256, 256, 0, stream>>>(dstI, E, deg);
    int nb = (N + 1023) / 1024;
    k_scan1<<<nb, 256, 0, stream>>>(deg, rowptr, bsum, N);
    k_scan2<<<1, 256, 0, stream>>>(bsum, nb);
    k_scan3<<<(N + 255) / 256, 256, 0, stream>>>(rowptr, bsum, N, E);
    k_scatter<<<(E + 255) / 256, 256, 0, stream>>>(srcI, dstI, E, rowptr, cursor, csr);

    // dtype prep
    k_cvtX<<<((N * 128 / 4) + 255) / 256, 256, 0, stream>>>(x, xbf, N * 128 / 4);
    k_cvtW<<<(4 * 64 * 128 + 255) / 256, 256, 0, stream>>>(Wq1, Wk1, Wv1, Ws1, WT1, 128);
    k_cvtW<<<(4 * 64 * 64 + 255) / 256, 256, 0, stream>>>(Wq2, Wk2, Wv2, Ws2, WT2, 64);

    dim3 gg((N + 63) / 64, 4);
    // layer 1
    k_gemm_mfma<128><<<gg, 256, 0, stream>>>(xbf, N, WT1, bq1, bk1, bv1, bs1,
                                             qb, kb, vb, sb);
    k_attn<<<(N + 3) / 4, 256, 0, stream>>>(qb, kb, vb, sb, rowptr, csr, hbf, N, 1, 1);
    // layer 2
    k_gemm_mfma<64><<<gg, 256, 0, stream>>>(hbf, N, WT2, bq2, bk2, bv2, bs2,
                                            qb, kb, vb, sb);
    k_attn<<<(N + 3) / 4, 256, 0, stream>>>(qb, kb, vb, sb, rowptr, csr, d_out, N, 0, 0);
}

// Round 10
// 537.233 us; speedup vs baseline: 1.7240x; 1.1645x over previous
//
#include <hip/hip_runtime.h>

typedef __attribute__((ext_vector_type(8))) short short8;
typedef __attribute__((ext_vector_type(4))) float f32x4;

__device__ __forceinline__ unsigned short f2bf(float f) {
    unsigned u = __float_as_uint(f);
    unsigned r = (u + 0x7fff + ((u >> 16) & 1)) >> 16;  // RNE
    return (unsigned short)r;
}
__device__ __forceinline__ float bf2f(unsigned short h) {
    return __uint_as_float(((unsigned)h) << 16);
}
__device__ __forceinline__ float bflo(unsigned u) { return __uint_as_float(u << 16); }
__device__ __forceinline__ float bfhi(unsigned u) { return __uint_as_float(u & 0xffff0000u); }

// ======== CSR build: two-level counting sort, no global atomics ========
// bucket = dst >> 9 (512 nodes/bucket, <=256 buckets for N<=131072)

#define NB1 64

// P1a: per-block bucket histogram (LDS atomics only)
__global__ __launch_bounds__(256) void k_sort1a(const int* __restrict__ dst, int E, int chunk,
                                                int* __restrict__ hist1) {
    __shared__ int h[256];
    int b = blockIdx.x, t = threadIdx.x;
    h[t] = 0;
    __syncthreads();
    int start = b * chunk, end = min(start + chunk, E);
    for (int i = start + t; i < end; i += 256) atomicAdd(&h[dst[i] >> 9], 1);
    __syncthreads();
    hist1[b * 256 + t] = h[t];
}

// P1b: hist1[b][t] -> exclusive prefix within bucket t; bOff[t] = bucket start
__global__ __launch_bounds__(256) void k_sort1b(int* __restrict__ hist1, int* __restrict__ bOff,
                                                int E) {
    __shared__ int tot[256];
    __shared__ int sc[256];
    int t = threadIdx.x;
    int run = 0;
    for (int b = 0; b < NB1; ++b) {
        int idx = b * 256 + t;
        int c = hist1[idx];
        hist1[idx] = run;
        run += c;
    }
    tot[t] = run;
    sc[t] = run;
    __syncthreads();
    for (int off = 1; off < 256; off <<= 1) {
        int x = (t >= off) ? sc[t - off] : 0;
        __syncthreads();
        sc[t] += x;
        __syncthreads();
    }
    bOff[t] = sc[t] - tot[t];
    if (t == 0) bOff[256] = E;
}

// P1c: scatter (dst,src) into bucket-contiguous buf1 (LDS cursors)
__global__ __launch_bounds__(256) void k_sort1c(const int* __restrict__ src,
                                                const int* __restrict__ dst, int E, int chunk,
                                                const int* __restrict__ hist1,
                                                const int* __restrict__ bOff,
                                                int2* __restrict__ buf1) {
    __shared__ int cur[256];
    int b = blockIdx.x, t = threadIdx.x;
    cur[t] = hist1[b * 256 + t];
    __syncthreads();
    int start = b * chunk, end = min(start + chunk, E);
    for (int i = start + t; i < end; i += 256) {
        int d = dst[i];
        int bkt = d >> 9;
        int r = atomicAdd(&cur[bkt], 1);
        buf1[bOff[bkt] + r] = make_int2(d, src[i]);
    }
}

// P2: one block per bucket — in-LDS 512-bin counting sort -> rowptr + csr
__global__ __launch_bounds__(256) void k_sort2(const int2* __restrict__ buf1,
                                               const int* __restrict__ bOff,
                                               int* __restrict__ rowptr, int* __restrict__ csr,
                                               int n, int E) {
    __shared__ int cnt[512];
    __shared__ int scn[512];
    __shared__ int part[256];
    int b = blockIdx.x, t = threadIdx.x;
    int lo = bOff[b], hi = bOff[b + 1];
    cnt[t] = 0;
    cnt[t + 256] = 0;
    __syncthreads();
    for (int i = lo + t; i < hi; i += 256) atomicAdd(&cnt[buf1[i].x & 511], 1);
    __syncthreads();
    int a0 = cnt[2 * t], a1 = cnt[2 * t + 1];
    part[t] = a0 + a1;
    __syncthreads();
    for (int off = 1; off < 256; off <<= 1) {
        int x = (t >= off) ? part[t - off] : 0;
        __syncthreads();
        part[t] += x;
        __syncthreads();
    }
    int excl = part[t] - (a0 + a1);
    scn[2 * t] = excl;
    scn[2 * t + 1] = excl + a0;
    __syncthreads();
    int node0 = b << 9;
    for (int j = t; j < 512; j += 256) {
        int node = node0 + j;
        if (node < n) rowptr[node] = lo + scn[j];
    }
    if (b == 0 && t == 0) rowptr[n] = E;
    // reuse cnt as cursors
    cnt[t] = 0;
    cnt[t + 256] = 0;
    __syncthreads();
    for (int i = lo + t; i < hi; i += 256) {
        int2 e = buf1[i];
        int d = e.x & 511;
        int r = atomicAdd(&cnt[d], 1);
        csr[lo + scn[d] + r] = e.y;
    }
}

// -------- dtype conversion --------

__global__ void k_cvtX(const float* __restrict__ X, unsigned short* __restrict__ Xbf, int total4) {
    int i = blockIdx.x * blockDim.x + threadIdx.x;
    if (i < total4) {
        float4 v = *(const float4*)(X + (size_t)i * 4);
        ushort4 o;
        o.x = f2bf(v.x); o.y = f2bf(v.y); o.z = f2bf(v.z); o.w = f2bf(v.w);
        *(ushort4*)(Xbf + (size_t)i * 4) = o;
    }
}

// WT[slot][64][K] = bf16( W_slot[k][j] )
__global__ void k_cvtW(const float* __restrict__ W0, const float* __restrict__ W1,
                       const float* __restrict__ W2, const float* __restrict__ W3,
                       unsigned short* __restrict__ WT, int K) {
    int idx = blockIdx.x * blockDim.x + threadIdx.x;
    int tot = 4 * 64 * K;
    if (idx >= tot) return;
    int slot = idx / (64 * K);
    int rem = idx % (64 * K);
    int j = rem / K, k = rem % K;
    const float* W = (slot == 0) ? W0 : (slot == 1) ? W1 : (slot == 2) ? W2 : W3;
    WT[idx] = f2bf(W[k * 64 + j]);
}

// -------- MFMA GEMM: O_slot = Xbf @ W_slot + b_slot,  [n,64] per slot --------

template <int K>
__global__ __launch_bounds__(256) void k_gemm_mfma(
    const unsigned short* __restrict__ Xbf, int n,
    const unsigned short* __restrict__ WT,
    const float* __restrict__ b0, const float* __restrict__ b1,
    const float* __restrict__ b2, const float* __restrict__ b3,
    void* __restrict__ O0, void* __restrict__ O1,
    void* __restrict__ O2, void* __restrict__ O3) {
    const int slot = blockIdx.y;
    const float* B = (slot == 0) ? b0 : (slot == 1) ? b1 : (slot == 2) ? b2 : b3;
    void* O = (slot == 0) ? O0 : (slot == 1) ? O1 : (slot == 2) ? O2 : O3;
    const bool isbf = (slot == 1 || slot == 2);

    __shared__ unsigned short xs[64 * K];
    __shared__ unsigned short ws[64 * K];
    const int t = threadIdx.x;
    const int row0 = blockIdx.x * 64;
    const int K2 = K * 2;
    const int CPR = K / 8;

    const unsigned short* wslot = WT + (size_t)slot * 64 * K;
    for (int c = t; c < 64 * CPR; c += 256) {
        int row = c / CPR, chunk = c % CPR;
        int grow = row0 + row;
        uint4 v = make_uint4(0, 0, 0, 0);
        if (grow < n) v = *(const uint4*)(Xbf + (size_t)grow * K + chunk * 8);
        int byte = (row * K2 + chunk * 16) ^ ((row & 7) << 4);
        *(uint4*)((char*)xs + byte) = v;
        uint4 wv = *(const uint4*)(wslot + (size_t)row * K + chunk * 8);
        *(uint4*)((char*)ws + byte) = wv;
    }
    __syncthreads();

    const int w = t >> 6, l = t & 63;
    const int lr = l & 15, lg = l >> 4;
    f32x4 acc[4];
#pragma unroll
    for (int j = 0; j < 4; ++j) acc[j] = (f32x4){0.f, 0.f, 0.f, 0.f};

#pragma unroll
    for (int ks = 0; ks < K / 32; ++ks) {
        int kb_ = (ks * 32 + lg * 8) * 2;
        int arow = w * 16 + lr;
        short8 a = *(const short8*)((char*)xs + ((arow * K2 + kb_) ^ ((arow & 7) << 4)));
#pragma unroll
        for (int j = 0; j < 4; ++j) {
            int brow = j * 16 + lr;
            short8 b = *(const short8*)((char*)ws + ((brow * K2 + kb_) ^ ((brow & 7) << 4)));
            acc[j] = __builtin_amdgcn_mfma_f32_16x16x32_bf16(a, b, acc[j], 0, 0, 0);
        }
    }

#pragma unroll
    for (int j = 0; j < 4; ++j) {
        int col = j * 16 + lr;
        float bv = B[col];
#pragma unroll
        for (int r = 0; r < 4; ++r) {
            int grow = row0 + w * 16 + lg * 4 + r;
            if (grow < n) {
                float val = acc[j][r] + bv;
                if (isbf) ((unsigned short*)O)[(size_t)grow * 64 + col] = f2bf(val);
                else      ((float*)O)[(size_t)grow * 64 + col] = val;
            }
        }
    }
}

// -------- fused attention: one wave per destination node --------
// 8 lanes per edge (bf16x8 = 16B/lane), 8 edges in flight per wave iteration.

__global__ __launch_bounds__(256) void k_attn(
    const float* __restrict__ q, const unsigned short* __restrict__ kk,
    const unsigned short* __restrict__ vv,
    const float* __restrict__ skip, const int* __restrict__ rowptr, const int* __restrict__ csr,
    void* __restrict__ out, int n, int dorelu, int obf) {
    int wid = threadIdx.x >> 6, lane = threadIdx.x & 63;
    int node = blockIdx.x * 4 + wid;
    if (node >= n) return;
    int start = rowptr[node];
    int deg = rowptr[node + 1] - start;
    int g = lane >> 3;   // edge slot 0..7
    int cl = lane & 7;   // channel octet
    const float* qrow = q + (size_t)node * 64 + cl * 8;
    float4 qa = *(const float4*)qrow;
    float4 qb_ = *(const float4*)(qrow + 4);
    float a0 = 0.f, a1 = 0.f, a2 = 0.f, a3 = 0.f, a4 = 0.f, a5 = 0.f, a6 = 0.f, a7 = 0.f;
    float sumex = 0.f;
#pragma unroll 2
    for (int j0 = 0; j0 < deg; j0 += 8) {
        int jj = j0 + g;
        bool act = jj < deg;
        int s_ = act ? csr[start + jj] : 0;
        uint4 kr = *(const uint4*)(kk + (size_t)s_ * 64 + cl * 8);
        float d = qa.x * bflo(kr.x) + qa.y * bfhi(kr.x) + qa.z * bflo(kr.y) + qa.w * bfhi(kr.y) +
                  qb_.x * bflo(kr.z) + qb_.y * bfhi(kr.z) + qb_.z * bflo(kr.w) + qb_.w * bfhi(kr.w);
        d += __shfl_xor(d, 1);
        d += __shfl_xor(d, 2);
        d += __shfl_xor(d, 4);
        float ex = act ? __expf(d * 0.125f) : 0.f;  // 1/sqrt(64)
        sumex += ex;
        uint4 vr = *(const uint4*)(vv + (size_t)s_ * 64 + cl * 8);
        a0 += ex * bflo(vr.x); a1 += ex * bfhi(vr.x);
        a2 += ex * bflo(vr.y); a3 += ex * bfhi(vr.y);
        a4 += ex * bflo(vr.z); a5 += ex * bfhi(vr.z);
        a6 += ex * bflo(vr.w); a7 += ex * bfhi(vr.w);
    }
#define RED3(v) v += __shfl_xor(v, 8); v += __shfl_xor(v, 16); v += __shfl_xor(v, 32);
    RED3(a0) RED3(a1) RED3(a2) RED3(a3) RED3(a4) RED3(a5) RED3(a6) RED3(a7) RED3(sumex)
#undef RED3
    if (g == 0) {
        float r = 1.0f / fmaxf(sumex, 1e-16f);
        const float* srow = skip + (size_t)node * 64 + cl * 8;
        float4 sa = *(const float4*)srow;
        float4 sb = *(const float4*)(srow + 4);
        float o0 = a0 * r + sa.x, o1 = a1 * r + sa.y, o2 = a2 * r + sa.z, o3 = a3 * r + sa.w;
        float o4 = a4 * r + sb.x, o5 = a5 * r + sb.y, o6 = a6 * r + sb.z, o7 = a7 * r + sb.w;
        if (dorelu) {
            o0 = fmaxf(o0, 0.f); o1 = fmaxf(o1, 0.f); o2 = fmaxf(o2, 0.f); o3 = fmaxf(o3, 0.f);
            o4 = fmaxf(o4, 0.f); o5 = fmaxf(o5, 0.f); o6 = fmaxf(o6, 0.f); o7 = fmaxf(o7, 0.f);
        }
        if (obf) {
            uint4 st;
            st.x = (unsigned)f2bf(o0) | ((unsigned)f2bf(o1) << 16);
            st.y = (unsigned)f2bf(o2) | ((unsigned)f2bf(o3) << 16);
            st.z = (unsigned)f2bf(o4) | ((unsigned)f2bf(o5) << 16);
            st.w = (unsigned)f2bf(o6) | ((unsigned)f2bf(o7) << 16);
            *(uint4*)((unsigned short*)out + (size_t)node * 64 + cl * 8) = st;
        } else {
            float* orow = (float*)out + (size_t)node * 64 + cl * 8;
            *(float4*)orow = make_float4(o0, o1, o2, o3);
            *(float4*)(orow + 4) = make_float4(o4, o5, o6, o7);
        }
    }
}

// -------- launch --------

extern "C" void kernel_launch(void* const* d_in, const int* in_sizes, int n_in,
                              void* d_out, int out_size, void* d_ws, size_t ws_size,
                              hipStream_t stream) {
    const float* x = (const float*)d_in[0];
    const int* ei = (const int*)d_in[1];
    // d_in[2] = edge_attr (ignored, edge_dim=None)
    const float* Wq1 = (const float*)d_in[3];  const float* bq1 = (const float*)d_in[4];
    const float* Wk1 = (const float*)d_in[5];  const float* bk1 = (const float*)d_in[6];
    const float* Wv1 = (const float*)d_in[7];  const float* bv1 = (const float*)d_in[8];
    const float* Ws1 = (const float*)d_in[9];  const float* bs1 = (const float*)d_in[10];
    const float* Wq2 = (const float*)d_in[11]; const float* bq2 = (const float*)d_in[12];
    const float* Wk2 = (const float*)d_in[13]; const float* bk2 = (const float*)d_in[14];
    const float* Wv2 = (const float*)d_in[15]; const float* bv2 = (const float*)d_in[16];
    const float* Ws2 = (const float*)d_in[17]; const float* bs2 = (const float*)d_in[18];

    const int N = in_sizes[0] / 128;
    const int E = in_sizes[1] / 2;
    const int* srcI = ei;
    const int* dstI = ei + E;

    char* w = (char*)d_ws;
    auto alloc = [&](size_t bytes) {
        void* p = (void*)w;
        w += (bytes + 255) & ~(size_t)255;
        return p;
    };
    int* hist1  = (int*)alloc((size_t)NB1 * 256 * 4);
    int* bOff   = (int*)alloc(257 * 4);
    int2* buf1  = (int2*)alloc((size_t)E * 8);
    int* rowptr = (int*)alloc((size_t)(N + 1) * 4);
    int* csr    = (int*)alloc((size_t)E * 4);
    float* qb          = (float*)alloc((size_t)N * 64 * 4);
    unsigned short* kb = (unsigned short*)alloc((size_t)N * 64 * 2);
    unsigned short* vb = (unsigned short*)alloc((size_t)N * 64 * 2);
    float* sb          = (float*)alloc((size_t)N * 64 * 4);
    unsigned short* xbf = (unsigned short*)alloc((size_t)N * 128 * 2);
    unsigned short* hbf = xbf;  // alias: xbf dead after gemm1
    unsigned short* WT1 = (unsigned short*)alloc((size_t)4 * 64 * 128 * 2);
    unsigned short* WT2 = (unsigned short*)alloc((size_t)4 * 64 * 64 * 2);

    const int chunk = (E + NB1 - 1) / NB1;
    const int nbuk = (N + 511) >> 9;

    k_sort1a<<<NB1, 256, 0, stream>>>(dstI, E, chunk, hist1);
    k_sort1b<<<1, 256, 0, stream>>>(hist1, bOff, E);
    k_sort1c<<<NB1, 256, 0, stream>>>(srcI, dstI, E, chunk, hist1, bOff, buf1);
    k_sort2<<<nbuk, 256, 0, stream>>>(buf1, bOff, rowptr, csr, N, E);

    k_cvtX<<<((N * 128 / 4) + 255) / 256, 256, 0, stream>>>(x, xbf, N * 128 / 4);
    k_cvtW<<<(4 * 64 * 128 + 255) / 256, 256, 0, stream>>>(Wq1, Wk1, Wv1, Ws1, WT1, 128);
    k_cvtW<<<(4 * 64 * 64 + 255) / 256, 256, 0, stream>>>(Wq2, Wk2, Wv2, Ws2, WT2, 64);

    dim3 gg((N + 63) / 64, 4);
    // layer 1
    k_gemm_mfma<128><<<gg, 256, 0, stream>>>(xbf, N, WT1, bq1, bk1, bv1, bs1,
                                             qb, kb, vb, sb);
    k_attn<<<(N + 3) / 4, 256, 0, stream>>>(qb, kb, vb, sb, rowptr, csr, hbf, N, 1, 1);
    // layer 2
    k_gemm_mfma<64><<<gg, 256, 0, stream>>>(hbf, N, WT2, bq2, bk2, bv2, bs2,
                                            qb, kb, vb, sb);
    k_attn<<<(N + 3) / 4, 256, 0, stream>>>(qb, kb, vb, sb, rowptr, csr, d_out, N, 0, 0);
}

// Round 14
// 497.147 us; speedup vs baseline: 1.8630x; 1.0806x over previous
//
#include <hip/hip_runtime.h>

typedef __attribute__((ext_vector_type(8))) short short8;
typedef __attribute__((ext_vector_type(4))) float f32x4;

__device__ __forceinline__ unsigned short f2bf(float f) {
    unsigned u = __float_as_uint(f);
    unsigned r = (u + 0x7fff + ((u >> 16) & 1)) >> 16;  // RNE
    return (unsigned short)r;
}
__device__ __forceinline__ float bf2f(unsigned short h) {
    return __uint_as_float(((unsigned)h) << 16);
}
__device__ __forceinline__ float bflo(unsigned u) { return __uint_as_float(u << 16); }
__device__ __forceinline__ float bfhi(unsigned u) { return __uint_as_float(u & 0xffff0000u); }

// ======== CSR build: block-reservation counting sort ========
// bucket = dst >> 7 (128 nodes/bucket, <=1024 buckets for N<=131072)
// A) global bucket totals   B) scan -> bOff, gcur   C) reserve+scatter   D) per-bucket 128-bin sort

#define BSH 7
#define NBUK_MAX 1024
#define CHUNK_MAX 1536

// A: bucket histogram, many blocks, LDS hist -> global atomic totals
__global__ __launch_bounds__(256) void k_histA(const int* __restrict__ dst, int E, int chunk,
                                               int nbuk, int* __restrict__ tot) {
    __shared__ int h[NBUK_MAX];
    int b = blockIdx.x, t = threadIdx.x;
    for (int j = t; j < NBUK_MAX; j += 256) h[j] = 0;
    __syncthreads();
    int start = b * chunk, end = min(start + chunk, E);
    for (int i = start + t; i < end; i += 256) atomicAdd(&h[dst[i] >> BSH], 1);
    __syncthreads();
    for (int j = t; j < nbuk; j += 256) {
        int v = h[j];
        if (v) atomicAdd(&tot[j], v);
    }
}

// B: exclusive scan of tot -> bOff (nbuk+1), copy to gcur
__global__ __launch_bounds__(256) void k_scanB(const int* __restrict__ tot, int* __restrict__ bOff,
                                               int* __restrict__ gcur, int nbuk, int E) {
    __shared__ int s[256];
    int t = threadIdx.x;
    int base = t * 4;
    int v0 = (base + 0 < nbuk) ? tot[base + 0] : 0;
    int v1 = (base + 1 < nbuk) ? tot[base + 1] : 0;
    int v2 = (base + 2 < nbuk) ? tot[base + 2] : 0;
    int v3 = (base + 3 < nbuk) ? tot[base + 3] : 0;
    int ts = v0 + v1 + v2 + v3;
    s[t] = ts;
    __syncthreads();
    for (int off = 1; off < 256; off <<= 1) {
        int x = (t >= off) ? s[t - off] : 0;
        __syncthreads();
        s[t] += x;
        __syncthreads();
    }
    int excl = s[t] - ts;
    int e0 = excl, e1 = excl + v0, e2 = excl + v0 + v1, e3 = excl + v0 + v1 + v2;
    if (base + 0 < nbuk) { bOff[base + 0] = e0; gcur[base + 0] = e0; }
    if (base + 1 < nbuk) { bOff[base + 1] = e1; gcur[base + 1] = e1; }
    if (base + 2 < nbuk) { bOff[base + 2] = e2; gcur[base + 2] = e2; }
    if (base + 3 < nbuk) { bOff[base + 3] = e3; gcur[base + 3] = e3; }
    if (t == 0) bOff[nbuk] = E;
}

// C: per-block LDS histogram -> reserve ranges in gcur -> scatter via LDS cursors
__global__ __launch_bounds__(256) void k_scatB(const int* __restrict__ src,
                                               const int* __restrict__ dst, int E, int chunk,
                                               int nbuk, int* __restrict__ gcur,
                                               int2* __restrict__ buf1) {
    __shared__ int ldst[CHUNK_MAX];
    __shared__ int h[NBUK_MAX];
    __shared__ int bas[NBUK_MAX];
    int b = blockIdx.x, t = threadIdx.x;
    for (int j = t; j < NBUK_MAX; j += 256) h[j] = 0;
    __syncthreads();
    int start = b * chunk, end = min(start + chunk, E);
    for (int i = start + t; i < end; i += 256) {
        int d = dst[i];
        ldst[i - start] = d;
        atomicAdd(&h[d >> BSH], 1);
    }
    __syncthreads();
    for (int j = t; j < nbuk; j += 256) {
        int c = h[j];
        if (c) bas[j] = atomicAdd(&gcur[j], c);
    }
    __syncthreads();
    for (int j = t; j < NBUK_MAX; j += 256) h[j] = 0;
    __syncthreads();
    for (int i = start + t; i < end; i += 256) {
        int d = ldst[i - start];
        int bkt = d >> BSH;
        int r = atomicAdd(&h[bkt], 1);
        buf1[bas[bkt] + r] = make_int2(d, src[i]);
    }
}

// D: one block per bucket — 128-bin in-LDS counting sort -> rowptr + csr
__global__ __launch_bounds__(256) void k_sort2(const int2* __restrict__ buf1,
                                               const int* __restrict__ bOff,
                                               int* __restrict__ rowptr, int* __restrict__ csr,
                                               int n, int E) {
    __shared__ int cnt[128];
    __shared__ int exc[128];
    __shared__ int sc[128];
    int b = blockIdx.x, t = threadIdx.x;
    int lo = bOff[b], hi = bOff[b + 1];
    if (t < 128) cnt[t] = 0;
    __syncthreads();
    for (int i = lo + t; i < hi; i += 256) atomicAdd(&cnt[buf1[i].x & 127], 1);
    __syncthreads();
    int c0 = (t < 128) ? cnt[t] : 0;
    if (t < 128) sc[t] = c0;
    __syncthreads();
    for (int off = 1; off < 128; off <<= 1) {
        int x = (t < 128 && t >= off) ? sc[t - off] : 0;
        __syncthreads();
        if (t < 128) sc[t] += x;
        __syncthreads();
    }
    if (t < 128) {
        int e = sc[t] - c0;
        exc[t] = e;
        int node = (b << BSH) + t;
        if (node < n) rowptr[node] = lo + e;
        cnt[t] = 0;  // reuse as cursor
    }
    if (b == 0 && t == 0) rowptr[n] = E;
    __syncthreads();
    for (int i = lo + t; i < hi; i += 256) {
        int2 e = buf1[i];
        int bin = e.x & 127;
        int r = atomicAdd(&cnt[bin], 1);
        csr[lo + exc[bin] + r] = e.y;
    }
}

// -------- dtype conversion --------

__global__ void k_cvtX(const float* __restrict__ X, unsigned short* __restrict__ Xbf, int total4) {
    int i = blockIdx.x * blockDim.x + threadIdx.x;
    if (i < total4) {
        float4 v = *(const float4*)(X + (size_t)i * 4);
        ushort4 o;
        o.x = f2bf(v.x); o.y = f2bf(v.y); o.z = f2bf(v.z); o.w = f2bf(v.w);
        *(ushort4*)(Xbf + (size_t)i * 4) = o;
    }
}

// WT[slot][64][K] = bf16( W_slot[k][j] )
__global__ void k_cvtW(const float* __restrict__ W0, const float* __restrict__ W1,
                       const float* __restrict__ W2, const float* __restrict__ W3,
                       unsigned short* __restrict__ WT, int K) {
    int idx = blockIdx.x * blockDim.x + threadIdx.x;
    int tot = 4 * 64 * K;
    if (idx >= tot) return;
    int slot = idx / (64 * K);
    int rem = idx % (64 * K);
    int j = rem / K, k = rem % K;
    const float* W = (slot == 0) ? W0 : (slot == 1) ? W1 : (slot == 2) ? W2 : W3;
    WT[idx] = f2bf(W[k * 64 + j]);
}

// -------- MFMA GEMM: O_slot = Xbf @ W_slot + b_slot,  [n,64] per slot --------

template <int K>
__global__ __launch_bounds__(256) void k_gemm_mfma(
    const unsigned short* __restrict__ Xbf, int n,
    const unsigned short* __restrict__ WT,
    const float* __restrict__ b0, const float* __restrict__ b1,
    const float* __restrict__ b2, const float* __restrict__ b3,
    void* __restrict__ O0, void* __restrict__ O1,
    void* __restrict__ O2, void* __restrict__ O3) {
    const int slot = blockIdx.y;
    const float* B = (slot == 0) ? b0 : (slot == 1) ? b1 : (slot == 2) ? b2 : b3;
    void* O = (slot == 0) ? O0 : (slot == 1) ? O1 : (slot == 2) ? O2 : O3;
    const bool isbf = (slot == 1 || slot == 2);

    __shared__ unsigned short xs[64 * K];
    __shared__ unsigned short ws[64 * K];
    const int t = threadIdx.x;
    const int row0 = blockIdx.x * 64;
    const int K2 = K * 2;
    const int CPR = K / 8;

    const unsigned short* wslot = WT + (size_t)slot * 64 * K;
    for (int c = t; c < 64 * CPR; c += 256) {
        int row = c / CPR, chunk = c % CPR;
        int grow = row0 + row;
        uint4 v = make_uint4(0, 0, 0, 0);
        if (grow < n) v = *(const uint4*)(Xbf + (size_t)grow * K + chunk * 8);
        int byte = (row * K2 + chunk * 16) ^ ((row & 7) << 4);
        *(uint4*)((char*)xs + byte) = v;
        uint4 wv = *(const uint4*)(wslot + (size_t)row * K + chunk * 8);
        *(uint4*)((char*)ws + byte) = wv;
    }
    __syncthreads();

    const int w = t >> 6, l = t & 63;
    const int lr = l & 15, lg = l >> 4;
    f32x4 acc[4];
#pragma unroll
    for (int j = 0; j < 4; ++j) acc[j] = (f32x4){0.f, 0.f, 0.f, 0.f};

#pragma unroll
    for (int ks = 0; ks < K / 32; ++ks) {
        int kb_ = (ks * 32 + lg * 8) * 2;
        int arow = w * 16 + lr;
        short8 a = *(const short8*)((char*)xs + ((arow * K2 + kb_) ^ ((arow & 7) << 4)));
#pragma unroll
        for (int j = 0; j < 4; ++j) {
            int brow = j * 16 + lr;
            short8 b = *(const short8*)((char*)ws + ((brow * K2 + kb_) ^ ((brow & 7) << 4)));
            acc[j] = __builtin_amdgcn_mfma_f32_16x16x32_bf16(a, b, acc[j], 0, 0, 0);
        }
    }

#pragma unroll
    for (int j = 0; j < 4; ++j) {
        int col = j * 16 + lr;
        float bv = B[col];
#pragma unroll
        for (int r = 0; r < 4; ++r) {
            int grow = row0 + w * 16 + lg * 4 + r;
            if (grow < n) {
                float val = acc[j][r] + bv;
                if (isbf) ((unsigned short*)O)[(size_t)grow * 64 + col] = f2bf(val);
                else      ((float*)O)[(size_t)grow * 64 + col] = val;
            }
        }
    }
}

// -------- fused attention: one wave per destination node --------
// 8 lanes per edge (bf16x8 = 16B/lane), 8 edges in flight per wave iteration.

__global__ __launch_bounds__(256) void k_attn(
    const float* __restrict__ q, const unsigned short* __restrict__ kk,
    const unsigned short* __restrict__ vv,
    const float* __restrict__ skip, const int* __restrict__ rowptr, const int* __restrict__ csr,
    void* __restrict__ out, int n, int dorelu, int obf) {
    int wid = threadIdx.x >> 6, lane = threadIdx.x & 63;
    int node = blockIdx.x * 4 + wid;
    if (node >= n) return;
    int start = rowptr[node];
    int deg = rowptr[node + 1] - start;
    int g = lane >> 3;   // edge slot 0..7
    int cl = lane & 7;   // channel octet
    const float* qrow = q + (size_t)node * 64 + cl * 8;
    float4 qa = *(const float4*)qrow;
    float4 qb_ = *(const float4*)(qrow + 4);
    float a0 = 0.f, a1 = 0.f, a2 = 0.f, a3 = 0.f, a4 = 0.f, a5 = 0.f, a6 = 0.f, a7 = 0.f;
    float sumex = 0.f;
#pragma unroll 2
    for (int j0 = 0; j0 < deg; j0 += 8) {
        int jj = j0 + g;
        bool act = jj < deg;
        int s_ = act ? csr[start + jj] : 0;
        uint4 kr = *(const uint4*)(kk + (size_t)s_ * 64 + cl * 8);
        float d = qa.x * bflo(kr.x) + qa.y * bfhi(kr.x) + qa.z * bflo(kr.y) + qa.w * bfhi(kr.y) +
                  qb_.x * bflo(kr.z) + qb_.y * bfhi(kr.z) + qb_.z * bflo(kr.w) + qb_.w * bfhi(kr.w);
        d += __shfl_xor(d, 1);
        d += __shfl_xor(d, 2);
        d += __shfl_xor(d, 4);
        float ex = act ? __expf(d * 0.125f) : 0.f;  // 1/sqrt(64)
        sumex += ex;
        uint4 vr = *(const uint4*)(vv + (size_t)s_ * 64 + cl * 8);
        a0 += ex * bflo(vr.x); a1 += ex * bfhi(vr.x);
        a2 += ex * bflo(vr.y); a3 += ex * bfhi(vr.y);
        a4 += ex * bflo(vr.z); a5 += ex * bfhi(vr.z);
        a6 += ex * bflo(vr.w); a7 += ex * bfhi(vr.w);
    }
#define RED3(v) v += __shfl_xor(v, 8); v += __shfl_xor(v, 16); v += __shfl_xor(v, 32);
    RED3(a0) RED3(a1) RED3(a2) RED3(a3) RED3(a4) RED3(a5) RED3(a6) RED3(a7) RED3(sumex)
#undef RED3
    if (g == 0) {
        float r = 1.0f / fmaxf(sumex, 1e-16f);
        const float* srow = skip + (size_t)node * 64 + cl * 8;
        float4 sa = *(const float4*)srow;
        float4 sb = *(const float4*)(srow + 4);
        float o0 = a0 * r + sa.x, o1 = a1 * r + sa.y, o2 = a2 * r + sa.z, o3 = a3 * r + sa.w;
        float o4 = a4 * r + sb.x, o5 = a5 * r + sb.y, o6 = a6 * r + sb.z, o7 = a7 * r + sb.w;
        if (dorelu) {
            o0 = fmaxf(o0, 0.f); o1 = fmaxf(o1, 0.f); o2 = fmaxf(o2, 0.f); o3 = fmaxf(o3, 0.f);
            o4 = fmaxf(o4, 0.f); o5 = fmaxf(o5, 0.f); o6 = fmaxf(o6, 0.f); o7 = fmaxf(o7, 0.f);
        }
        if (obf) {
            uint4 st;
            st.x = (unsigned)f2bf(o0) | ((unsigned)f2bf(o1) << 16);
            st.y = (unsigned)f2bf(o2) | ((unsigned)f2bf(o3) << 16);
            st.z = (unsigned)f2bf(o4) | ((unsigned)f2bf(o5) << 16);
            st.w = (unsigned)f2bf(o6) | ((unsigned)f2bf(o7) << 16);
            *(uint4*)((unsigned short*)out + (size_t)node * 64 + cl * 8) = st;
        } else {
            float* orow = (float*)out + (size_t)node * 64 + cl * 8;
            *(float4*)orow = make_float4(o0, o1, o2, o3);
            *(float4*)(orow + 4) = make_float4(o4, o5, o6, o7);
        }
    }
}

// -------- launch --------

extern "C" void kernel_launch(void* const* d_in, const int* in_sizes, int n_in,
                              void* d_out, int out_size, void* d_ws, size_t ws_size,
                              hipStream_t stream) {
    const float* x = (const float*)d_in[0];
    const int* ei = (const int*)d_in[1];
    // d_in[2] = edge_attr (ignored, edge_dim=None)
    const float* Wq1 = (const float*)d_in[3];  const float* bq1 = (const float*)d_in[4];
    const float* Wk1 = (const float*)d_in[5];  const float* bk1 = (const float*)d_in[6];
    const float* Wv1 = (const float*)d_in[7];  const float* bv1 = (const float*)d_in[8];
    const float* Ws1 = (const float*)d_in[9];  const float* bs1 = (const float*)d_in[10];
    const float* Wq2 = (const float*)d_in[11]; const float* bq2 = (const float*)d_in[12];
    const float* Wk2 = (const float*)d_in[13]; const float* bk2 = (const float*)d_in[14];
    const float* Wv2 = (const float*)d_in[15]; const float* bv2 = (const float*)d_in[16];
    const float* Ws2 = (const float*)d_in[17]; const float* bs2 = (const float*)d_in[18];

    const int N = in_sizes[0] / 128;
    const int E = in_sizes[1] / 2;
    const int* srcI = ei;
    const int* dstI = ei + E;

    char* w = (char*)d_ws;
    auto alloc = [&](size_t bytes) {
        void* p = (void*)w;
        w += (bytes + 255) & ~(size_t)255;
        return p;
    };
    int* tot    = (int*)alloc((size_t)NBUK_MAX * 4);
    int* bOff   = (int*)alloc((size_t)(NBUK_MAX + 1) * 4);
    int* gcur   = (int*)alloc((size_t)NBUK_MAX * 4);
    int2* buf1  = (int2*)alloc((size_t)E * 8);
    int* rowptr = (int*)alloc((size_t)(N + 1) * 4);
    int* csr    = (int*)alloc((size_t)E * 4);
    float* qb          = (float*)alloc((size_t)N * 64 * 4);
    unsigned short* kb = (unsigned short*)alloc((size_t)N * 64 * 2);
    unsigned short* vb = (unsigned short*)alloc((size_t)N * 64 * 2);
    float* sb          = (float*)alloc((size_t)N * 64 * 4);
    unsigned short* xbf = (unsigned short*)alloc((size_t)N * 128 * 2);
    unsigned short* hbf = xbf;  // alias: xbf dead after gemm1
    unsigned short* WT1 = (unsigned short*)alloc((size_t)4 * 64 * 128 * 2);
    unsigned short* WT2 = (unsigned short*)alloc((size_t)4 * 64 * 64 * 2);

    const int nbuk = (N + ((1 << BSH) - 1)) >> BSH;          // 128-node buckets
    const int NB1 = (E + (CHUNK_MAX - 1)) / CHUNK_MAX;       // scatter blocks
    const int chunk = (E + NB1 - 1) / NB1;                   // <= CHUNK_MAX

    hipMemsetAsync(tot, 0, (size_t)NBUK_MAX * 4, stream);

    k_histA<<<NB1, 256, 0, stream>>>(dstI, E, chunk, nbuk, tot);
    k_scanB<<<1, 256, 0, stream>>>(tot, bOff, gcur, nbuk, E);
    k_scatB<<<NB1, 256, 0, stream>>>(srcI, dstI, E, chunk, nbuk, gcur, buf1);
    k_sort2<<<nbuk, 256, 0, stream>>>(buf1, bOff, rowptr, csr, N, E);

    k_cvtX<<<((N * 128 / 4) + 255) / 256, 256, 0, stream>>>(x, xbf, N * 128 / 4);
    k_cvtW<<<(4 * 64 * 128 + 255) / 256, 256, 0, stream>>>(Wq1, Wk1, Wv1, Ws1, WT1, 128);
    k_cvtW<<<(4 * 64 * 64 + 255) / 256, 256, 0, stream>>>(Wq2, Wk2, Wv2, Ws2, WT2, 64);

    dim3 gg((N + 63) / 64, 4);
    // layer 1
    k_gemm_mfma<128><<<gg, 256, 0, stream>>>(xbf, N, WT1, bq1, bk1, bv1, bs1,
                                             qb, kb, vb, sb);
    k_attn<<<(N + 3) / 4, 256, 0, stream>>>(qb, kb, vb, sb, rowptr, csr, hbf, N, 1, 1);
    // layer 2
    k_gemm_mfma<64><<<gg, 256, 0, stream>>>(hbf, N, WT2, bq2, bk2, bv2, bs2,
                                            qb, kb, vb, sb);
    k_attn<<<(N + 3) / 4, 256, 0, stream>>>(qb, kb, vb, sb, rowptr, csr, d_out, N, 0, 0);
}